// Round 6
// baseline (192.676 us; speedup 1.0000x reference)
//
#include <hip/hip_runtime.h>
#include <hip/hip_bf16.h>
#include <stdint.h>

typedef unsigned short u16;
typedef unsigned int u32;
typedef __attribute__((ext_vector_type(8))) short short8;
typedef __attribute__((ext_vector_type(4))) float float4v;
typedef __attribute__((ext_vector_type(2))) float float2v;

#define CH 128
#define OO 128
#define KD 1152      // 9*128
#define MPIX 32768   // 8*64*64

__device__ __forceinline__ u16 f2bf(float v) {
    __hip_bfloat16 h = __float2bfloat16(v);
    return *reinterpret_cast<u16*>(&h);
}

__device__ __forceinline__ float bf_lo(u32 u) {      // low bf16 of pair -> f32 (exact)
    u32 t = u << 16;
    return __builtin_bit_cast(float, t);
}
__device__ __forceinline__ float bf_hi(u32 u) {      // high bf16 of pair -> f32 (exact)
    u32 t = u & 0xffff0000u;
    return __builtin_bit_cast(float, t);
}
__device__ __forceinline__ float2v unpk(u32 u) {
    float2v r;
    r.x = bf_lo(u);
    r.y = bf_hi(u);
    return r;
}
// pack two f32 -> bf16 pair; scalar casts let the compiler fuse to v_cvt_pk_bf16_f32
__device__ __forceinline__ u32 pack_bf16(float lo, float hi) {
    return (u32)f2bf(lo) | ((u32)f2bf(hi) << 16);
}

// ---------------- merged prep: transpose + offset_conv + wreorder ----------------
__global__ __launch_bounds__(256) void prep_kernel(const float* __restrict__ x,
                                                   const float* __restrict__ w_off,
                                                   const float* __restrict__ w_main,
                                                   __hip_bfloat16* __restrict__ xt,
                                                   float* __restrict__ partial,
                                                   u16* __restrict__ Wb) {
    __shared__ float st[64][65];
    int tid = threadIdx.x;
    int bid = blockIdx.x;

    if (bid < 512) {
        // ---- transpose ----
        int bh = bid;                     // b*64 + h
        int b = bh >> 6;
        int h = bh & 63;
        const float* xb = x + ((size_t)b * CH) * 4096 + (size_t)h * 64;
        u32* xo32 = (u32*)(xt + ((size_t)bh << 6) * CH);   // row stride 64 u32
        for (int cc0 = 0; cc0 < 128; cc0 += 64) {
            #pragma unroll
            for (int step = 0; step < 16; ++step) {
                int cl = (tid >> 6) + step * 4;
                int w = tid & 63;
                st[cl][w] = xb[(size_t)(cc0 + cl) * 4096 + w];
            }
            __syncthreads();
            // packed pair stores: 32 lanes x u32 = 128B contiguous per w-row
            #pragma unroll
            for (int step = 0; step < 8; ++step) {
                int w = (tid >> 5) + step * 8;
                int p = tid & 31;
                u32 pair = pack_bf16(st[2 * p][w], st[2 * p + 1][w]);
                xo32[(size_t)w * 64 + (cc0 >> 1) + p] = pair;
            }
            __syncthreads();
        }
    } else if (bid < 1024) {
        // ---- offset conv ----
        int idx = bid - 512;
        int m = (idx & 127) * 256 + tid;
        int chunk = idx >> 7;             // 0..3, 32 channels each
        int b = m >> 12;
        int hw = m & 4095;
        int h = hw >> 6;
        int w = hw & 63;
        float acc[6] = {0.f, 0.f, 0.f, 0.f, 0.f, 0.f};
        int c0 = chunk * 32;
        for (int c = c0; c < c0 + 32; ++c) {
            const float* xc = x + ((size_t)(b * CH + c) << 12);
            float xv[9];
            #pragma unroll
            for (int dy = 0; dy < 3; ++dy) {
                int yy = h + dy - 1;
                bool vy = (unsigned)yy < 64u;
                #pragma unroll
                for (int dx = 0; dx < 3; ++dx) {
                    int xx = w + dx - 1;
                    bool vv = vy && ((unsigned)xx < 64u);
                    xv[dy * 3 + dx] = vv ? xc[yy * 64 + xx] : 0.f;
                }
            }
            const float* wb = w_off + (size_t)c * 9;
            #pragma unroll
            for (int s = 0; s < 6; ++s) {
                int chn = (s < 3) ? s * 6 : (s - 3) * 2 + 1;
                const float* wp = wb + (size_t)chn * (CH * 9);
                float a = acc[s];
                #pragma unroll
                for (int t = 0; t < 9; ++t) a = fmaf(xv[t], wp[t], a);
                acc[s] = a;
            }
        }
        float* po = partial + ((size_t)(chunk << 15) + m) * 6;
        #pragma unroll
        for (int s = 0; s < 6; ++s) po[s] = acc[s];
    } else {
        // ---- weight reorder ----
        int idx = (bid - 1024) * 256 + tid;
        if (idx < OO * KD) {
            int o = idx / KD;
            int r = idx - o * KD;
            int k = r >> 7;
            int c = r & 127;
            Wb[idx] = f2bf(w_main[(size_t)o * KD + c * 9 + k]);
        }
    }
}

// ---------------- fused deformable-sample + GEMM ----------------
// One block = 32 pixels x all 128 outputs; grid 1024 -> 4 blocks/CU (16 waves/CU)
// to hide gather latency (round-5 counters: 2 blocks/CU was latency-bound).
// XCD-affinity: bid&7 = image -> per-XCD L2-resident xt slice.
// A tile (128x32) staged to LDS with coalesced 64B row segments + register
// ping-pong prefetch; B tile (32x32) gathered+blended by waves 0-1.
// Double-buffered lA/lB: ONE barrier per K-step (WAR-safe as in round 3).
__global__ __launch_bounds__(256, 4) void fused_gemm_kernel(const __hip_bfloat16* __restrict__ xt,
                                                            const float* __restrict__ partial,
                                                            const float* __restrict__ b_off,
                                                            const u16* __restrict__ Wb,
                                                            const float* __restrict__ b_main,
                                                            float* __restrict__ out) {
    __shared__ float offs[32][6];
    __shared__ __align__(16) float4v twt[32][9];   // bilinear weights per (pix, tap)
    __shared__ __align__(16) int4 tbs[32][9];      // corner base offsets (u32-pair units)
    __shared__ __align__(16) u16 lA[2][128 * 32];  // weight tile dbuf
    __shared__ __align__(16) u16 lB[2][32 * 32];   // sample tile dbuf

    int tid = threadIdx.x;
    int orig = blockIdx.x;
    int b = orig & 7;                 // image == XCD
    int idx = orig >> 3;              // 0..127
    int h = idx >> 1;                 // row within image
    int w0 = (idx & 1) << 5;          // 32-pixel half of the row
    int m0 = (((b << 6) + h) << 6) + w0;

    // -- prologue 1: gather offsets (6 per pixel, 32 pixels) --
    if (tid < 192) {
        int pix = tid / 6, s = tid % 6;
        int m = m0 + pix;
        int chn = (s < 3) ? s * 6 : (s - 3) * 2 + 1;
        float v = b_off[chn];
        #pragma unroll
        for (int q = 0; q < 4; ++q) v += partial[((size_t)(q << 15) + m) * 6 + s];
        offs[pix][s] = v;
    }
    __syncthreads();

    // -- prologue 2: per-(pix,tap) bilinear weights + corner bases --
    for (int i2 = tid; i2 < 32 * 9; i2 += 256) {
        int pix = i2 / 9, k = i2 % 9;
        int i = k / 3, j = k - i * 3;
        float ox = offs[pix][0];
        if (i >= 1) ox += offs[pix][1];
        if (i >= 2) ox += offs[pix][2];
        float oy = offs[pix][3];
        if (j >= 1) oy += offs[pix][4];
        if (j >= 2) oy += offs[pix][5];
        const float step = 2.0f / 63.0f;
        float bxn = -1.0f + (w0 + pix) * step;
        float byn = -1.0f + h * step;
        float gx = fmaf(bxn + ox, 32.0f, 31.5f);
        float gy = fmaf(byn + oy, 32.0f, 31.5f);
        float x0f = floorf(gx), y0f = floorf(gy);
        float wx = gx - x0f, wy = gy - y0f;
        int ix0 = (int)x0f, iy0 = (int)y0f;
        int ix1 = ix0 + 1, iy1 = iy0 + 1;
        float fx0 = ((unsigned)ix0 < 64u) ? 1.f : 0.f;
        float fx1 = ((unsigned)ix1 < 64u) ? 1.f : 0.f;
        float fy0 = ((unsigned)iy0 < 64u) ? 1.f : 0.f;
        float fy1 = ((unsigned)iy1 < 64u) ? 1.f : 0.f;
        float4v wv;
        wv[0] = (1.f - wy) * (1.f - wx) * fy0 * fx0;
        wv[1] = (1.f - wy) * wx * fy0 * fx1;
        wv[2] = wy * (1.f - wx) * fy1 * fx0;
        wv[3] = wy * wx * fy1 * fx1;
        int cx0 = min(max(ix0, 0), 63), cx1 = min(max(ix1, 0), 63);
        int cy0 = min(max(iy0, 0), 63), cy1 = min(max(iy1, 0), 63);
        twt[pix][k] = wv;
        tbs[pix][k] = make_int4((cy0 * 64 + cx0) * 64, (cy0 * 64 + cx1) * 64,
                                (cy1 * 64 + cx0) * 64, (cy1 * 64 + cx1) * 64);
    }
    __syncthreads();

    // -- main loop setup --
    int wave = tid >> 6, lane = tid & 63;
    int mrow = lane & 15;
    int q8 = (lane >> 4) * 8;

    // A staging: thread -> rows (tid>>2) and (tid>>2)+64, col group (tid&3)*8
    int ar = tid >> 2;
    int ag = (tid & 3) * 8;
    const u16* aptr0 = Wb + (size_t)ar * KD + ag;
    const u16* aptr1 = aptr0 + (size_t)64 * KD;
    int asto = ar * 32 + ag;

    // B staging (waves 0-1 only): pix = tid>>2 (0..31), 8-ch group (tid&3)*8
    int pixB = tid >> 2;
    int cgp = (tid & 3) * 8;
    const u32* xb = (const u32*)(xt + (((size_t)b << 12) * (size_t)CH));  // bf16 pairs
    int bsto = (tid >> 2 & 31) * 32 + cgp;
    bool bstager = tid < 128;

    float4v acc[2][2];
    #pragma unroll
    for (int sm = 0; sm < 2; ++sm)
        #pragma unroll
        for (int sn = 0; sn < 2; ++sn)
            acc[sm][sn] = (float4v){0.f, 0.f, 0.f, 0.f};

    float4v wv;
    int4 bv;
    uint4 u00, u01, u10, u11;

    auto issueB = [&](int kk) {
        if ((kk & 3) == 0) {
            int k = kk >> 2;
            wv = twt[pixB][k];
            bv = tbs[pixB][k];
        }
        const u32* xc = xb + ((((kk & 3) << 5) + cgp) >> 1);
        u00 = *(const uint4*)(xc + bv.x);
        u01 = *(const uint4*)(xc + bv.y);
        u10 = *(const uint4*)(xc + bv.z);
        u11 = *(const uint4*)(xc + bv.w);
    };
    auto issueA = [&](int kk, uint4* dst) {
        dst[0] = *(const uint4*)(aptr0 + kk * 32);
        dst[1] = *(const uint4*)(aptr1 + kk * 32);
    };

    auto dostep = [&](int kk, uint4* aC, uint4* aN) {
        u16* lAc = &lA[kk & 1][0];
        u16* lBc = &lB[kk & 1][0];

        *(uint4*)&lAc[asto] = aC[0];
        *(uint4*)&lAc[asto + 64 * 32] = aC[1];
        if (bstager) {
            const u32* p00 = (const u32*)&u00;
            const u32* p01 = (const u32*)&u01;
            const u32* p10 = (const u32*)&u10;
            const u32* p11 = (const u32*)&u11;
            u32 outp[4];
            #pragma unroll
            for (int q = 0; q < 4; ++q) {
                float2v p = unpk(p00[q]) * wv[0];
                p += unpk(p01[q]) * wv[1];
                p += unpk(p10[q]) * wv[2];
                p += unpk(p11[q]) * wv[3];
                outp[q] = pack_bf16(p.x, p.y);
            }
            *(uint4*)&lBc[bsto] = *(const uint4*)outp;
        }

        if (kk < 35) {                // prefetch step kk+1
            issueA(kk + 1, aN);
            if (bstager) issueB(kk + 1);
        }

        __syncthreads();              // the ONLY barrier per step

        short8 af[2], bfv[2];
        #pragma unroll
        for (int s = 0; s < 2; ++s)
            af[s] = *(const short8*)&lAc[(wave * 32 + s * 16 + mrow) * 32 + q8];
        #pragma unroll
        for (int s = 0; s < 2; ++s)
            bfv[s] = *(const short8*)&lBc[(s * 16 + mrow) * 32 + q8];
        #pragma unroll
        for (int sm = 0; sm < 2; ++sm)
            #pragma unroll
            for (int sn = 0; sn < 2; ++sn)
                acc[sm][sn] = __builtin_amdgcn_mfma_f32_16x16x32_bf16(af[sm], bfv[sn],
                                                                     acc[sm][sn], 0, 0, 0);
    };

    uint4 aP[2], aQ[2];
    issueA(0, aP);
    if (bstager) issueB(0);
    for (int t = 0; t < 18; ++t) {    // 36 steps, ping-pong A-frag registers
        dostep(2 * t, aP, aQ);
        dostep(2 * t + 1, aQ, aP);
    }

    // epilogue: C/D layout col=lane&15 (pixel), row=(lane>>4)*4+r (o)
    #pragma unroll
    for (int sm = 0; sm < 2; ++sm) {
        int o = wave * 32 + sm * 16 + (lane >> 4) * 4;
        #pragma unroll
        for (int sn = 0; sn < 2; ++sn) {
            int pcol = m0 + sn * 16 + mrow;
            int rem = pcol & 4095;
            float* op = out + (((size_t)b * OO) << 12) + rem;
            #pragma unroll
            for (int r = 0; r < 4; ++r)
                op[(size_t)(o + r) << 12] = acc[sm][sn][r] + b_main[o + r];
        }
    }
}

extern "C" void kernel_launch(void* const* d_in, const int* in_sizes, int n_in,
                              void* d_out, int out_size, void* d_ws, size_t ws_size,
                              hipStream_t stream) {
    const float* x      = (const float*)d_in[0];
    const float* w_off  = (const float*)d_in[1];
    const float* b_off  = (const float*)d_in[2];
    const float* w_main = (const float*)d_in[3];
    const float* b_main = (const float*)d_in[4];
    float* out = (float*)d_out;

    char* ws = (char*)d_ws;
    __hip_bfloat16* xt = (__hip_bfloat16*)ws;                         // 8 MB
    float* partial = (float*)(ws + 8388608);                          // 3 MB
    u16* Wb   = (u16*)(ws + 8388608 + 3145728);                       // 288 KB

    prep_kernel<<<1600, 256, 0, stream>>>(x, w_off, w_main, xt, partial, Wb);
    fused_gemm_kernel<<<MPIX / 32, 256, 0, stream>>>(xt, partial, b_off, Wb, b_main, out);
}

// Round 7
// 132.067 us; speedup vs baseline: 1.4589x; 1.4589x over previous
//
#include <hip/hip_runtime.h>
#include <hip/hip_bf16.h>
#include <stdint.h>

typedef unsigned short u16;
typedef unsigned int u32;
typedef __attribute__((ext_vector_type(8))) short short8;
typedef __attribute__((ext_vector_type(4))) float float4v;
typedef __attribute__((ext_vector_type(2))) float float2v;

#define CH 128
#define OO 128
#define KD 1152      // 9*128
#define MPIX 32768   // 8*64*64

__device__ __forceinline__ u16 f2bf(float v) {
    __hip_bfloat16 h = __float2bfloat16(v);
    return *reinterpret_cast<u16*>(&h);
}

__device__ __forceinline__ float bf_lo(u32 u) {      // low bf16 of pair -> f32 (exact)
    u32 t = u << 16;
    return __builtin_bit_cast(float, t);
}
__device__ __forceinline__ float bf_hi(u32 u) {      // high bf16 of pair -> f32 (exact)
    u32 t = u & 0xffff0000u;
    return __builtin_bit_cast(float, t);
}
__device__ __forceinline__ float2v unpk(u32 u) {
    float2v r;
    r.x = bf_lo(u);
    r.y = bf_hi(u);
    return r;
}
// pack two f32 -> bf16 pair; scalar casts let the compiler fuse to v_cvt_pk_bf16_f32
__device__ __forceinline__ u32 pack_bf16(float lo, float hi) {
    return (u32)f2bf(lo) | ((u32)f2bf(hi) << 16);
}

// ---------------- merged prep: transpose + offset_conv + wreorder ----------------
__global__ __launch_bounds__(256) void prep_kernel(const float* __restrict__ x,
                                                   const float* __restrict__ w_off,
                                                   const float* __restrict__ w_main,
                                                   __hip_bfloat16* __restrict__ xt,
                                                   float* __restrict__ partial,
                                                   u16* __restrict__ Wb) {
    __shared__ float st[64][65];
    int tid = threadIdx.x;
    int bid = blockIdx.x;

    if (bid < 512) {
        // ---- transpose ----
        int bh = bid;                     // b*64 + h
        int b = bh >> 6;
        int h = bh & 63;
        const float* xb = x + ((size_t)b * CH) * 4096 + (size_t)h * 64;
        u32* xo32 = (u32*)(xt + ((size_t)bh << 6) * CH);   // row stride 64 u32
        for (int cc0 = 0; cc0 < 128; cc0 += 64) {
            #pragma unroll
            for (int step = 0; step < 16; ++step) {
                int cl = (tid >> 6) + step * 4;
                int w = tid & 63;
                st[cl][w] = xb[(size_t)(cc0 + cl) * 4096 + w];
            }
            __syncthreads();
            // packed pair stores: 32 lanes x u32 = 128B contiguous per w-row
            #pragma unroll
            for (int step = 0; step < 8; ++step) {
                int w = (tid >> 5) + step * 8;
                int p = tid & 31;
                u32 pair = pack_bf16(st[2 * p][w], st[2 * p + 1][w]);
                xo32[(size_t)w * 64 + (cc0 >> 1) + p] = pair;
            }
            __syncthreads();
        }
    } else if (bid < 1024) {
        // ---- offset conv ----
        int idx = bid - 512;
        int m = (idx & 127) * 256 + tid;
        int chunk = idx >> 7;             // 0..3, 32 channels each
        int b = m >> 12;
        int hw = m & 4095;
        int h = hw >> 6;
        int w = hw & 63;
        float acc[6] = {0.f, 0.f, 0.f, 0.f, 0.f, 0.f};
        int c0 = chunk * 32;
        for (int c = c0; c < c0 + 32; ++c) {
            const float* xc = x + ((size_t)(b * CH + c) << 12);
            float xv[9];
            #pragma unroll
            for (int dy = 0; dy < 3; ++dy) {
                int yy = h + dy - 1;
                bool vy = (unsigned)yy < 64u;
                #pragma unroll
                for (int dx = 0; dx < 3; ++dx) {
                    int xx = w + dx - 1;
                    bool vv = vy && ((unsigned)xx < 64u);
                    xv[dy * 3 + dx] = vv ? xc[yy * 64 + xx] : 0.f;
                }
            }
            const float* wb = w_off + (size_t)c * 9;
            #pragma unroll
            for (int s = 0; s < 6; ++s) {
                int chn = (s < 3) ? s * 6 : (s - 3) * 2 + 1;
                const float* wp = wb + (size_t)chn * (CH * 9);
                float a = acc[s];
                #pragma unroll
                for (int t = 0; t < 9; ++t) a = fmaf(xv[t], wp[t], a);
                acc[s] = a;
            }
        }
        float* po = partial + ((size_t)(chunk << 15) + m) * 6;
        #pragma unroll
        for (int s = 0; s < 6; ++s) po[s] = acc[s];
    } else {
        // ---- weight reorder ----
        int idx = (bid - 1024) * 256 + tid;
        if (idx < OO * KD) {
            int o = idx / KD;
            int r = idx - o * KD;
            int k = r >> 7;
            int c = r & 127;
            Wb[idx] = f2bf(w_main[(size_t)o * KD + c * 9 + k]);
        }
    }
}

// ---------------- fused deformable-sample + GEMM ----------------
// One block = 32 pixels x all 128 outputs; grid 1024 -> 4 blocks/CU (grid-fed
// occupancy; round-6 lesson: do NOT force it via __launch_bounds__ min-waves,
// that spilled the pipeline state to scratch: VGPR 52 + 193MB scratch writes).
// XCD-affinity: bid&7 = image -> per-XCD L2-resident xt slice.
// A tile (128x32) staged to LDS (coalesced 64B row segments) with NAMED
// register ping-pong prefetch; B tile (32x32) gathered+blended by waves 0-1.
// Double-buffered lA/lB: ONE barrier per K-step (WAR-safe as in round 3).
__global__ __launch_bounds__(256) void fused_gemm_kernel(const __hip_bfloat16* __restrict__ xt,
                                                         const float* __restrict__ partial,
                                                         const float* __restrict__ b_off,
                                                         const u16* __restrict__ Wb,
                                                         const float* __restrict__ b_main,
                                                         float* __restrict__ out) {
    __shared__ float offs[32][6];
    __shared__ __align__(16) float4v twt[32][9];   // bilinear weights per (pix, tap)
    __shared__ __align__(16) int4 tbs[32][9];      // corner base offsets (u32-pair units)
    __shared__ __align__(16) u16 lA[2][128 * 32];  // weight tile dbuf
    __shared__ __align__(16) u16 lB[2][32 * 32];   // sample tile dbuf

    int tid = threadIdx.x;
    int orig = blockIdx.x;
    int b = orig & 7;                 // image == XCD
    int idx = orig >> 3;              // 0..127
    int h = idx >> 1;                 // row within image
    int w0 = (idx & 1) << 5;          // 32-pixel half of the row
    int m0 = (((b << 6) + h) << 6) + w0;

    // -- prologue 1: gather offsets (6 per pixel, 32 pixels) --
    if (tid < 192) {
        int pix = tid / 6, s = tid % 6;
        int m = m0 + pix;
        int chn = (s < 3) ? s * 6 : (s - 3) * 2 + 1;
        float v = b_off[chn];
        #pragma unroll
        for (int q = 0; q < 4; ++q) v += partial[((size_t)(q << 15) + m) * 6 + s];
        offs[pix][s] = v;
    }
    __syncthreads();

    // -- prologue 2: per-(pix,tap) bilinear weights + corner bases --
    for (int i2 = tid; i2 < 32 * 9; i2 += 256) {
        int pix = i2 / 9, k = i2 % 9;
        int i = k / 3, j = k - i * 3;
        float ox = offs[pix][0];
        if (i >= 1) ox += offs[pix][1];
        if (i >= 2) ox += offs[pix][2];
        float oy = offs[pix][3];
        if (j >= 1) oy += offs[pix][4];
        if (j >= 2) oy += offs[pix][5];
        const float step = 2.0f / 63.0f;
        float bxn = -1.0f + (w0 + pix) * step;
        float byn = -1.0f + h * step;
        float gx = fmaf(bxn + ox, 32.0f, 31.5f);
        float gy = fmaf(byn + oy, 32.0f, 31.5f);
        float x0f = floorf(gx), y0f = floorf(gy);
        float wx = gx - x0f, wy = gy - y0f;
        int ix0 = (int)x0f, iy0 = (int)y0f;
        int ix1 = ix0 + 1, iy1 = iy0 + 1;
        float fx0 = ((unsigned)ix0 < 64u) ? 1.f : 0.f;
        float fx1 = ((unsigned)ix1 < 64u) ? 1.f : 0.f;
        float fy0 = ((unsigned)iy0 < 64u) ? 1.f : 0.f;
        float fy1 = ((unsigned)iy1 < 64u) ? 1.f : 0.f;
        float4v wv;
        wv[0] = (1.f - wy) * (1.f - wx) * fy0 * fx0;
        wv[1] = (1.f - wy) * wx * fy0 * fx1;
        wv[2] = wy * (1.f - wx) * fy1 * fx0;
        wv[3] = wy * wx * fy1 * fx1;
        int cx0 = min(max(ix0, 0), 63), cx1 = min(max(ix1, 0), 63);
        int cy0 = min(max(iy0, 0), 63), cy1 = min(max(iy1, 0), 63);
        twt[pix][k] = wv;
        tbs[pix][k] = make_int4((cy0 * 64 + cx0) * 64, (cy0 * 64 + cx1) * 64,
                                (cy1 * 64 + cx0) * 64, (cy1 * 64 + cx1) * 64);
    }
    __syncthreads();

    // -- main loop setup --
    int wave = tid >> 6, lane = tid & 63;
    int mrow = lane & 15;
    int q8 = (lane >> 4) * 8;

    // A staging: thread -> rows (tid>>2) and (tid>>2)+64, col group (tid&3)*8
    int ar = tid >> 2;
    int ag = (tid & 3) * 8;
    const u16* aptr0 = Wb + (size_t)ar * KD + ag;
    const u16* aptr1 = aptr0 + (size_t)64 * KD;
    int asto = ar * 32 + ag;

    // B staging (waves 0-1 only): pix = tid>>2 (0..31), 8-ch group (tid&3)*8
    int pixB = tid >> 2;
    int cgp = (tid & 3) * 8;
    const u32* xb = (const u32*)(xt + (((size_t)b << 12) * (size_t)CH));  // bf16 pairs
    int bsto = (tid >> 2 & 31) * 32 + cgp;
    bool bstager = tid < 128;

    float4v acc[2][2];
    #pragma unroll
    for (int sm = 0; sm < 2; ++sm)
        #pragma unroll
        for (int sn = 0; sn < 2; ++sn)
            acc[sm][sn] = (float4v){0.f, 0.f, 0.f, 0.f};

    float4v wv;
    int4 bv;
    uint4 u00, u01, u10, u11;

    auto issueB = [&](int kk) {
        if ((kk & 3) == 0) {
            int k = kk >> 2;
            wv = twt[pixB][k];
            bv = tbs[pixB][k];
        }
        const u32* xc = xb + ((((kk & 3) << 5) + cgp) >> 1);
        u00 = *(const uint4*)(xc + bv.x);
        u01 = *(const uint4*)(xc + bv.y);
        u10 = *(const uint4*)(xc + bv.z);
        u11 = *(const uint4*)(xc + bv.w);
    };

    // named-register ping-pong A prefetch (no arrays -> no scratch risk)
    auto dostep = [&](int kk, uint4& c0, uint4& c1, uint4& n0, uint4& n1) {
        u16* lAc = &lA[kk & 1][0];
        u16* lBc = &lB[kk & 1][0];

        *(uint4*)&lAc[asto] = c0;
        *(uint4*)&lAc[asto + 64 * 32] = c1;
        if (bstager) {
            const u32* p00 = (const u32*)&u00;
            const u32* p01 = (const u32*)&u01;
            const u32* p10 = (const u32*)&u10;
            const u32* p11 = (const u32*)&u11;
            u32 outp[4];
            #pragma unroll
            for (int q = 0; q < 4; ++q) {
                float2v p = unpk(p00[q]) * wv[0];
                p += unpk(p01[q]) * wv[1];
                p += unpk(p10[q]) * wv[2];
                p += unpk(p11[q]) * wv[3];
                outp[q] = pack_bf16(p.x, p.y);
            }
            *(uint4*)&lBc[bsto] = *(const uint4*)outp;
        }

        if (kk < 35) {                // prefetch step kk+1
            n0 = *(const uint4*)(aptr0 + (kk + 1) * 32);
            n1 = *(const uint4*)(aptr1 + (kk + 1) * 32);
            if (bstager) issueB(kk + 1);
        }

        __syncthreads();              // the ONLY barrier per step

        short8 af[2], bfv[2];
        #pragma unroll
        for (int s = 0; s < 2; ++s)
            af[s] = *(const short8*)&lAc[(wave * 32 + s * 16 + mrow) * 32 + q8];
        #pragma unroll
        for (int s = 0; s < 2; ++s)
            bfv[s] = *(const short8*)&lBc[(s * 16 + mrow) * 32 + q8];
        #pragma unroll
        for (int sm = 0; sm < 2; ++sm)
            #pragma unroll
            for (int sn = 0; sn < 2; ++sn)
                acc[sm][sn] = __builtin_amdgcn_mfma_f32_16x16x32_bf16(af[sm], bfv[sn],
                                                                     acc[sm][sn], 0, 0, 0);
    };

    uint4 aP0, aP1, aQ0, aQ1;
    aP0 = *(const uint4*)(aptr0);
    aP1 = *(const uint4*)(aptr1);
    if (bstager) issueB(0);
    for (int t = 0; t < 18; ++t) {    // 36 steps, ping-pong named A-frag regs
        dostep(2 * t, aP0, aP1, aQ0, aQ1);
        dostep(2 * t + 1, aQ0, aQ1, aP0, aP1);
    }

    // epilogue: C/D layout col=lane&15 (pixel), row=(lane>>4)*4+r (o)
    #pragma unroll
    for (int sm = 0; sm < 2; ++sm) {
        int o = wave * 32 + sm * 16 + (lane >> 4) * 4;
        #pragma unroll
        for (int sn = 0; sn < 2; ++sn) {
            int pcol = m0 + sn * 16 + mrow;
            int rem = pcol & 4095;
            float* op = out + (((size_t)b * OO) << 12) + rem;
            #pragma unroll
            for (int r = 0; r < 4; ++r)
                op[(size_t)(o + r) << 12] = acc[sm][sn][r] + b_main[o + r];
        }
    }
}

extern "C" void kernel_launch(void* const* d_in, const int* in_sizes, int n_in,
                              void* d_out, int out_size, void* d_ws, size_t ws_size,
                              hipStream_t stream) {
    const float* x      = (const float*)d_in[0];
    const float* w_off  = (const float*)d_in[1];
    const float* b_off  = (const float*)d_in[2];
    const float* w_main = (const float*)d_in[3];
    const float* b_main = (const float*)d_in[4];
    float* out = (float*)d_out;

    char* ws = (char*)d_ws;
    __hip_bfloat16* xt = (__hip_bfloat16*)ws;                         // 8 MB
    float* partial = (float*)(ws + 8388608);                          // 3 MB
    u16* Wb   = (u16*)(ws + 8388608 + 3145728);                       // 288 KB

    prep_kernel<<<1600, 256, 0, stream>>>(x, w_off, w_main, xt, partial, Wb);
    fused_gemm_kernel<<<MPIX / 32, 256, 0, stream>>>(xt, partial, b_off, Wb, b_main, out);
}

// Round 8
// 126.458 us; speedup vs baseline: 1.5236x; 1.0444x over previous
//
#include <hip/hip_runtime.h>
#include <hip/hip_bf16.h>
#include <stdint.h>

typedef unsigned short u16;
typedef unsigned int u32;
typedef __attribute__((ext_vector_type(8))) short short8;
typedef __attribute__((ext_vector_type(4))) float float4v;
typedef __attribute__((ext_vector_type(2))) float float2v;

#define CH 128
#define OO 128
#define KD 1152      // 9*128
#define MPIX 32768   // 8*64*64
#define LDBp 136     // lB row stride in u16 (128 ch + 8 pad: 2-way-free b128 reads)

__device__ __forceinline__ u16 f2bf(float v) {
    __hip_bfloat16 h = __float2bfloat16(v);
    return *reinterpret_cast<u16*>(&h);
}

__device__ __forceinline__ float bf_lo(u32 u) {      // low bf16 of pair -> f32 (exact)
    u32 t = u << 16;
    return __builtin_bit_cast(float, t);
}
__device__ __forceinline__ float bf_hi(u32 u) {      // high bf16 of pair -> f32 (exact)
    u32 t = u & 0xffff0000u;
    return __builtin_bit_cast(float, t);
}
__device__ __forceinline__ float2v unpk(u32 u) {
    float2v r;
    r.x = bf_lo(u);
    r.y = bf_hi(u);
    return r;
}
// pack two f32 -> bf16 pair; scalar casts fuse to v_cvt_pk_bf16_f32
__device__ __forceinline__ u32 pack_bf16(float lo, float hi) {
    return (u32)f2bf(lo) | ((u32)f2bf(hi) << 16);
}

// ---------------- merged prep: transpose + offset_conv + wreorder ----------------
__global__ __launch_bounds__(256) void prep_kernel(const float* __restrict__ x,
                                                   const float* __restrict__ w_off,
                                                   const float* __restrict__ w_main,
                                                   __hip_bfloat16* __restrict__ xt,
                                                   float* __restrict__ partial,
                                                   u16* __restrict__ Wb) {
    __shared__ float st[64][65];
    int tid = threadIdx.x;
    int bid = blockIdx.x;

    if (bid < 512) {
        // ---- transpose ----
        int bh = bid;                     // b*64 + h
        int b = bh >> 6;
        int h = bh & 63;
        const float* xb = x + ((size_t)b * CH) * 4096 + (size_t)h * 64;
        u32* xo32 = (u32*)(xt + ((size_t)bh << 6) * CH);   // row stride 64 u32
        for (int cc0 = 0; cc0 < 128; cc0 += 64) {
            #pragma unroll
            for (int step = 0; step < 16; ++step) {
                int cl = (tid >> 6) + step * 4;
                int w = tid & 63;
                st[cl][w] = xb[(size_t)(cc0 + cl) * 4096 + w];
            }
            __syncthreads();
            #pragma unroll
            for (int step = 0; step < 8; ++step) {
                int w = (tid >> 5) + step * 8;
                int p = tid & 31;
                u32 pair = pack_bf16(st[2 * p][w], st[2 * p + 1][w]);
                xo32[(size_t)w * 64 + (cc0 >> 1) + p] = pair;
            }
            __syncthreads();
        }
    } else if (bid < 1024) {
        // ---- offset conv ----
        int idx = bid - 512;
        int m = (idx & 127) * 256 + tid;
        int chunk = idx >> 7;             // 0..3, 32 channels each
        int b = m >> 12;
        int hw = m & 4095;
        int h = hw >> 6;
        int w = hw & 63;
        float acc[6] = {0.f, 0.f, 0.f, 0.f, 0.f, 0.f};
        int c0 = chunk * 32;
        for (int c = c0; c < c0 + 32; ++c) {
            const float* xc = x + ((size_t)(b * CH + c) << 12);
            float xv[9];
            #pragma unroll
            for (int dy = 0; dy < 3; ++dy) {
                int yy = h + dy - 1;
                bool vy = (unsigned)yy < 64u;
                #pragma unroll
                for (int dx = 0; dx < 3; ++dx) {
                    int xx = w + dx - 1;
                    bool vv = vy && ((unsigned)xx < 64u);
                    xv[dy * 3 + dx] = vv ? xc[yy * 64 + xx] : 0.f;
                }
            }
            const float* wb = w_off + (size_t)c * 9;
            #pragma unroll
            for (int s = 0; s < 6; ++s) {
                int chn = (s < 3) ? s * 6 : (s - 3) * 2 + 1;
                const float* wp = wb + (size_t)chn * (CH * 9);
                float a = acc[s];
                #pragma unroll
                for (int t = 0; t < 9; ++t) a = fmaf(xv[t], wp[t], a);
                acc[s] = a;
            }
        }
        float* po = partial + ((size_t)(chunk << 15) + m) * 6;
        #pragma unroll
        for (int s = 0; s < 6; ++s) po[s] = acc[s];
    } else {
        // ---- weight reorder ----
        int idx = (bid - 1024) * 256 + tid;
        if (idx < OO * KD) {
            int o = idx / KD;
            int r = idx - o * KD;
            int k = r >> 7;
            int c = r & 127;
            Wb[idx] = f2bf(w_main[(size_t)o * KD + c * 9 + k]);
        }
    }
}

// ---------------- fused deformable-sample + GEMM (per-tap B staging) ----------------
// One block = 64 pixels (one image row) x all 128 outputs; 512 blocks = 2/CU.
// XCD-affinity: bid&7 = image -> per-XCD L2-resident xt slice.
// B staged per TAP (64 pix x 128 ch): burst of 16 uint4 gathers per thread at
// tap-step 0, blended into LDS at steps 2-3 -> ~2.5 K-steps of latency slack,
// counted vmcnt (A prefetch trails the burst; never drains to 0).
// A tile staged per K-step (ping-pong regs, dbuf LDS); ONE barrier per K-step.
// WAR: lB[(t+1)&1] last read in tap t-1 (2 barriers before the writes in tap t).
__global__ __launch_bounds__(256, 2) void fused_gemm_kernel(const __hip_bfloat16* __restrict__ xt,
                                                            const float* __restrict__ partial,
                                                            const float* __restrict__ b_off,
                                                            const u16* __restrict__ Wb,
                                                            const float* __restrict__ b_main,
                                                            float* __restrict__ out) {
    __shared__ float offs[64][6];
    __shared__ __align__(16) float4v twt[64][9];   // bilinear weights per (pix, tap)
    __shared__ __align__(16) int4 tbs[64][9];      // corner row offsets (u32 units)
    __shared__ __align__(16) u16 lA[2][128 * 32];  // weight tile dbuf (per K-step)
    __shared__ __align__(16) u16 lB[2][64 * LDBp]; // sample tile dbuf (per tap)

    int tid = threadIdx.x;
    int orig = blockIdx.x;
    int b = orig & 7;                 // image == XCD
    int h = orig >> 3;                // row within image (0..63)
    int m0 = ((b << 6) + h) << 6;     // first pixel index

    // -- prologue 1: gather offsets (6 per pixel) --
    for (int idx = tid; idx < 64 * 6; idx += 256) {
        int pix = idx / 6, s = idx % 6;
        int m = m0 + pix;
        int chn = (s < 3) ? s * 6 : (s - 3) * 2 + 1;
        float v = b_off[chn];
        #pragma unroll
        for (int q = 0; q < 4; ++q) v += partial[((size_t)(q << 15) + m) * 6 + s];
        offs[pix][s] = v;
    }
    __syncthreads();

    // -- prologue 2: per-(pix,tap) bilinear weights + corner bases --
    for (int i2 = tid; i2 < 64 * 9; i2 += 256) {
        int pix = i2 / 9, k = i2 % 9;
        int i = k / 3, j = k - i * 3;
        float ox = offs[pix][0];
        if (i >= 1) ox += offs[pix][1];
        if (i >= 2) ox += offs[pix][2];
        float oy = offs[pix][3];
        if (j >= 1) oy += offs[pix][4];
        if (j >= 2) oy += offs[pix][5];
        const float step = 2.0f / 63.0f;
        float bxn = -1.0f + pix * step;
        float byn = -1.0f + h * step;
        float gx = fmaf(bxn + ox, 32.0f, 31.5f);
        float gy = fmaf(byn + oy, 32.0f, 31.5f);
        float x0f = floorf(gx), y0f = floorf(gy);
        float wx = gx - x0f, wy = gy - y0f;
        int ix0 = (int)x0f, iy0 = (int)y0f;
        int ix1 = ix0 + 1, iy1 = iy0 + 1;
        float fx0 = ((unsigned)ix0 < 64u) ? 1.f : 0.f;
        float fx1 = ((unsigned)ix1 < 64u) ? 1.f : 0.f;
        float fy0 = ((unsigned)iy0 < 64u) ? 1.f : 0.f;
        float fy1 = ((unsigned)iy1 < 64u) ? 1.f : 0.f;
        float4v wv;
        wv[0] = (1.f - wy) * (1.f - wx) * fy0 * fx0;
        wv[1] = (1.f - wy) * wx * fy0 * fx1;
        wv[2] = wy * (1.f - wx) * fy1 * fx0;
        wv[3] = wy * wx * fy1 * fx1;
        int cx0 = min(max(ix0, 0), 63), cx1 = min(max(ix1, 0), 63);
        int cy0 = min(max(iy0, 0), 63), cy1 = min(max(iy1, 0), 63);
        twt[pix][k] = wv;
        tbs[pix][k] = make_int4((cy0 * 64 + cx0) * 64, (cy0 * 64 + cx1) * 64,
                                (cy1 * 64 + cx0) * 64, (cy1 * 64 + cx1) * 64);
    }
    __syncthreads();

    // -- main loop setup --
    int wave = tid >> 6, lane = tid & 63;
    int wo = wave & 1;                // o half (64 rows each)
    int wp = wave >> 1;               // pixel half (32 each)
    int mrow = lane & 15;
    int q8 = (lane >> 4) * 8;

    // A staging: thread -> rows (tid>>2), (tid>>2)+64; col group (tid&3)*8
    int ar = tid >> 2;
    int ag = (tid & 3) * 8;
    const u16* aptr0 = Wb + (size_t)ar * KD + ag;
    const u16* aptr1 = aptr0 + (size_t)64 * KD;
    int asto = ar * 32 + ag;

    // B staging: thread -> pixel (tid>>2), 32-ch quarter (tid&3)
    int pixB = tid >> 2;              // 0..63
    int t4 = tid & 3;
    int t4o = t4 * 4;                 // u32 offset within each 64B chunk-slot
    const u32* xb = (const u32*)(xt + (((size_t)b << 12) * (size_t)CH));  // bf16 pairs
    int bwb = pixB * LDBp + t4 * 8;   // write base (u16); + q*32 per chunk

    float4v acc[4][2];
    #pragma unroll
    for (int sm = 0; sm < 4; ++sm)
        #pragma unroll
        for (int sn = 0; sn < 2; ++sn)
            acc[sm][sn] = (float4v){0.f, 0.f, 0.f, 0.f};

    float4v wv;
    int4 bv;
    uint4 u[4][4];                    // [corner][chunk] - static indices only

    auto burst = [&](int t) {         // issue 16 gathers + read tap tables
        wv = twt[pixB][t];
        bv = tbs[pixB][t];
        #pragma unroll
        for (int q = 0; q < 4; ++q) {
            u[0][q] = *(const uint4*)(xb + bv.x + q * 16 + t4o);
            u[1][q] = *(const uint4*)(xb + bv.y + q * 16 + t4o);
            u[2][q] = *(const uint4*)(xb + bv.z + q * 16 + t4o);
            u[3][q] = *(const uint4*)(xb + bv.w + q * 16 + t4o);
        }
    };

    auto blendq = [&](const uint4& a0, const uint4& a1, const uint4& a2,
                      const uint4& a3, int col, u16* lBw) {
        const u32* p00 = (const u32*)&a0;
        const u32* p01 = (const u32*)&a1;
        const u32* p10 = (const u32*)&a2;
        const u32* p11 = (const u32*)&a3;
        u32 outp[4];
        #pragma unroll
        for (int j = 0; j < 4; ++j) {
            float2v p = unpk(p00[j]) * wv[0];
            p += unpk(p01[j]) * wv[1];
            p += unpk(p10[j]) * wv[2];
            p += unpk(p11[j]) * wv[3];
            outp[j] = pack_bf16(p.x, p.y);
        }
        *(uint4*)&lBw[bwb + col] = *(const uint4*)outp;
    };

    auto stepA = [&](int kk, uint4& c0, uint4& c1, uint4& n0, uint4& n1, u16* lAc) {
        *(uint4*)&lAc[asto] = c0;
        *(uint4*)&lAc[asto + 64 * 32] = c1;
        if (kk + 1 < 36) {
            n0 = *(const uint4*)(aptr0 + (size_t)(kk + 1) * 32);
            n1 = *(const uint4*)(aptr1 + (size_t)(kk + 1) * 32);
        }
    };

    auto mfma_step = [&](const u16* lAc, const u16* lBr, int col) {
        short8 af[4], bfv[2];
        #pragma unroll
        for (int i = 0; i < 4; ++i)
            af[i] = *(const short8*)&lAc[(wo * 64 + i * 16 + mrow) * 32 + q8];
        #pragma unroll
        for (int sn = 0; sn < 2; ++sn)
            bfv[sn] = *(const short8*)&lBr[(wp * 32 + sn * 16 + mrow) * LDBp + col + q8];
        #pragma unroll
        for (int i = 0; i < 4; ++i)
            #pragma unroll
            for (int sn = 0; sn < 2; ++sn)
                acc[i][sn] = __builtin_amdgcn_mfma_f32_16x16x32_bf16(af[i], bfv[sn],
                                                                    acc[i][sn], 0, 0, 0);
    };

    // prologue: tap 0 burst + blend into lB[0]; first A step into regs
    uint4 aC0 = *(const uint4*)aptr0;
    uint4 aC1 = *(const uint4*)aptr1;
    uint4 aN0, aN1;
    burst(0);
    {
        u16* lBw = &lB[0][0];
        blendq(u[0][0], u[1][0], u[2][0], u[3][0], 0,  lBw);
        blendq(u[0][1], u[1][1], u[2][1], u[3][1], 32, lBw);
        blendq(u[0][2], u[1][2], u[2][2], u[3][2], 64, lBw);
        blendq(u[0][3], u[1][3], u[2][3], u[3][3], 96, lBw);
    }

    for (int t = 0; t < 9; ++t) {
        int kk = t * 4;
        const u16* lBr = &lB[t & 1][0];
        u16* lBw = &lB[(t + 1) & 1][0];
        u16* lA0 = &lA[0][0];
        u16* lA1 = &lA[1][0];
        bool more = t < 8;

        // s = 0: burst next tap's gathers (max slack), stage A
        if (more) burst(t + 1);
        stepA(kk, aC0, aC1, aN0, aN1, lA0);
        __syncthreads();
        mfma_step(lA0, lBr, 0);

        // s = 1
        stepA(kk + 1, aN0, aN1, aC0, aC1, lA1);
        __syncthreads();
        mfma_step(lA1, lBr, 32);

        // s = 2: blend first half of next tap's B tile
        stepA(kk + 2, aC0, aC1, aN0, aN1, lA0);
        if (more) {
            blendq(u[0][0], u[1][0], u[2][0], u[3][0], 0,  lBw);
            blendq(u[0][1], u[1][1], u[2][1], u[3][1], 32, lBw);
        }
        __syncthreads();
        mfma_step(lA0, lBr, 64);

        // s = 3: blend second half
        stepA(kk + 3, aN0, aN1, aC0, aC1, lA1);
        if (more) {
            blendq(u[0][2], u[1][2], u[2][2], u[3][2], 64, lBw);
            blendq(u[0][3], u[1][3], u[2][3], u[3][3], 96, lBw);
        }
        __syncthreads();
        mfma_step(lA1, lBr, 96);
    }

    // epilogue: C/D layout col=lane&15 (pixel), row=(lane>>4)*4+r (o)
    #pragma unroll
    for (int sm = 0; sm < 4; ++sm) {
        int o = wo * 64 + sm * 16 + (lane >> 4) * 4;
        #pragma unroll
        for (int sn = 0; sn < 2; ++sn) {
            int pcol = m0 + wp * 32 + sn * 16 + mrow;
            int rem = pcol & 4095;
            float* op = out + (((size_t)b * OO) << 12) + rem;
            #pragma unroll
            for (int r = 0; r < 4; ++r)
                op[(size_t)(o + r) << 12] = acc[sm][sn][r] + b_main[o + r];
        }
    }
}

extern "C" void kernel_launch(void* const* d_in, const int* in_sizes, int n_in,
                              void* d_out, int out_size, void* d_ws, size_t ws_size,
                              hipStream_t stream) {
    const float* x      = (const float*)d_in[0];
    const float* w_off  = (const float*)d_in[1];
    const float* b_off  = (const float*)d_in[2];
    const float* w_main = (const float*)d_in[3];
    const float* b_main = (const float*)d_in[4];
    float* out = (float*)d_out;

    char* ws = (char*)d_ws;
    __hip_bfloat16* xt = (__hip_bfloat16*)ws;                         // 8 MB
    float* partial = (float*)(ws + 8388608);                          // 3 MB
    u16* Wb   = (u16*)(ws + 8388608 + 3145728);                       // 288 KB

    prep_kernel<<<1600, 256, 0, stream>>>(x, w_off, w_main, xt, partial, Wb);
    fused_gemm_kernel<<<MPIX / 64, 256, 0, stream>>>(xt, partial, b_off, Wb, b_main, out);
}

// Round 9
// 126.137 us; speedup vs baseline: 1.5275x; 1.0025x over previous
//
#include <hip/hip_runtime.h>
#include <hip/hip_bf16.h>
#include <stdint.h>

typedef unsigned short u16;
typedef unsigned int u32;
typedef __attribute__((ext_vector_type(8))) short short8;
typedef __attribute__((ext_vector_type(4))) float float4v;
typedef __attribute__((ext_vector_type(2))) float float2v;

#define CH 128
#define OO 128
#define KD 1152      // 9*128
#define MPIX 32768   // 8*64*64
#define LDBp 136     // lB row stride in u16 (128 ch + 8 pad: 2-way-free b128 reads)

// Barrier that does NOT drain the vmem queue (HIP __syncthreads emits
// s_waitcnt vmcnt(0) before s_barrier, exposing ~200cy of L2 latency per step
// and defeating the gather-burst pipeline). LDS writes are drained (lgkmcnt)
// so cross-wave LDS data is visible; global loads here are register-destined
// (same-thread consumption), so they need no barrier coordination — the
// compiler inserts counted vmcnt(N) before each use. "memory" clobber pins
// load/store code motion across the fence. (m201-verified plain-HIP pattern.)
#define BAR_LDS() do { \
    asm volatile("s_waitcnt lgkmcnt(0)" ::: "memory"); \
    __builtin_amdgcn_s_barrier(); \
} while (0)

__device__ __forceinline__ u16 f2bf(float v) {
    __hip_bfloat16 h = __float2bfloat16(v);
    return *reinterpret_cast<u16*>(&h);
}

__device__ __forceinline__ float bf_lo(u32 u) {      // low bf16 of pair -> f32 (exact)
    u32 t = u << 16;
    return __builtin_bit_cast(float, t);
}
__device__ __forceinline__ float bf_hi(u32 u) {      // high bf16 of pair -> f32 (exact)
    u32 t = u & 0xffff0000u;
    return __builtin_bit_cast(float, t);
}
__device__ __forceinline__ float2v unpk(u32 u) {
    float2v r;
    r.x = bf_lo(u);
    r.y = bf_hi(u);
    return r;
}
// pack two f32 -> bf16 pair; scalar casts fuse to v_cvt_pk_bf16_f32
__device__ __forceinline__ u32 pack_bf16(float lo, float hi) {
    return (u32)f2bf(lo) | ((u32)f2bf(hi) << 16);
}

// ---------------- merged prep: transpose + offset_conv + wreorder ----------------
__global__ __launch_bounds__(256) void prep_kernel(const float* __restrict__ x,
                                                   const float* __restrict__ w_off,
                                                   const float* __restrict__ w_main,
                                                   __hip_bfloat16* __restrict__ xt,
                                                   float* __restrict__ partial,
                                                   u16* __restrict__ Wb) {
    __shared__ float st[64][65];
    int tid = threadIdx.x;
    int bid = blockIdx.x;

    if (bid < 512) {
        // ---- transpose ----
        int bh = bid;                     // b*64 + h
        int b = bh >> 6;
        int h = bh & 63;
        const float* xb = x + ((size_t)b * CH) * 4096 + (size_t)h * 64;
        u32* xo32 = (u32*)(xt + ((size_t)bh << 6) * CH);   // row stride 64 u32
        for (int cc0 = 0; cc0 < 128; cc0 += 64) {
            #pragma unroll
            for (int step = 0; step < 16; ++step) {
                int cl = (tid >> 6) + step * 4;
                int w = tid & 63;
                st[cl][w] = xb[(size_t)(cc0 + cl) * 4096 + w];
            }
            __syncthreads();
            #pragma unroll
            for (int step = 0; step < 8; ++step) {
                int w = (tid >> 5) + step * 8;
                int p = tid & 31;
                u32 pair = pack_bf16(st[2 * p][w], st[2 * p + 1][w]);
                xo32[(size_t)w * 64 + (cc0 >> 1) + p] = pair;
            }
            __syncthreads();
        }
    } else if (bid < 1024) {
        // ---- offset conv ----
        int idx = bid - 512;
        int m = (idx & 127) * 256 + tid;
        int chunk = idx >> 7;             // 0..3, 32 channels each
        int b = m >> 12;
        int hw = m & 4095;
        int h = hw >> 6;
        int w = hw & 63;
        float acc[6] = {0.f, 0.f, 0.f, 0.f, 0.f, 0.f};
        int c0 = chunk * 32;
        for (int c = c0; c < c0 + 32; ++c) {
            const float* xc = x + ((size_t)(b * CH + c) << 12);
            float xv[9];
            #pragma unroll
            for (int dy = 0; dy < 3; ++dy) {
                int yy = h + dy - 1;
                bool vy = (unsigned)yy < 64u;
                #pragma unroll
                for (int dx = 0; dx < 3; ++dx) {
                    int xx = w + dx - 1;
                    bool vv = vy && ((unsigned)xx < 64u);
                    xv[dy * 3 + dx] = vv ? xc[yy * 64 + xx] : 0.f;
                }
            }
            const float* wb = w_off + (size_t)c * 9;
            #pragma unroll
            for (int s = 0; s < 6; ++s) {
                int chn = (s < 3) ? s * 6 : (s - 3) * 2 + 1;
                const float* wp = wb + (size_t)chn * (CH * 9);
                float a = acc[s];
                #pragma unroll
                for (int t = 0; t < 9; ++t) a = fmaf(xv[t], wp[t], a);
                acc[s] = a;
            }
        }
        float* po = partial + ((size_t)(chunk << 15) + m) * 6;
        #pragma unroll
        for (int s = 0; s < 6; ++s) po[s] = acc[s];
    } else {
        // ---- weight reorder ----
        int idx = (bid - 1024) * 256 + tid;
        if (idx < OO * KD) {
            int o = idx / KD;
            int r = idx - o * KD;
            int k = r >> 7;
            int c = r & 127;
            Wb[idx] = f2bf(w_main[(size_t)o * KD + c * 9 + k]);
        }
    }
}

// ---------------- fused deformable-sample + GEMM (per-tap B staging) ----------------
// One block = 64 pixels (one image row) x all 128 outputs; 512 blocks = 2/CU.
// XCD-affinity: bid&7 = image -> per-XCD L2-resident xt slice.
// B staged per TAP (64 pix x 128 ch): burst of 16 uint4 gathers per thread at
// tap-step 0, blended into LDS at steps 2-3. With BAR_LDS (no vmcnt drain)
// the burst genuinely spans ~2.5 K-steps of MFMA+staging work.
// A tile staged per K-step (ping-pong regs, dbuf LDS); ONE barrier per K-step.
// WAR: every LDS buffer has >=2 barriers between last-read and next-write.
__global__ __launch_bounds__(256, 2) void fused_gemm_kernel(const __hip_bfloat16* __restrict__ xt,
                                                            const float* __restrict__ partial,
                                                            const float* __restrict__ b_off,
                                                            const u16* __restrict__ Wb,
                                                            const float* __restrict__ b_main,
                                                            float* __restrict__ out) {
    __shared__ float offs[64][6];
    __shared__ __align__(16) float4v twt[64][9];   // bilinear weights per (pix, tap)
    __shared__ __align__(16) int4 tbs[64][9];      // corner row offsets (u32 units)
    __shared__ __align__(16) u16 lA[2][128 * 32];  // weight tile dbuf (per K-step)
    __shared__ __align__(16) u16 lB[2][64 * LDBp]; // sample tile dbuf (per tap)

    int tid = threadIdx.x;
    int orig = blockIdx.x;
    int b = orig & 7;                 // image == XCD
    int h = orig >> 3;                // row within image (0..63)
    int m0 = ((b << 6) + h) << 6;     // first pixel index

    // -- prologue 1: gather offsets (6 per pixel) --
    for (int idx = tid; idx < 64 * 6; idx += 256) {
        int pix = idx / 6, s = idx % 6;
        int m = m0 + pix;
        int chn = (s < 3) ? s * 6 : (s - 3) * 2 + 1;
        float v = b_off[chn];
        #pragma unroll
        for (int q = 0; q < 4; ++q) v += partial[((size_t)(q << 15) + m) * 6 + s];
        offs[pix][s] = v;
    }
    __syncthreads();

    // -- prologue 2: per-(pix,tap) bilinear weights + corner bases --
    for (int i2 = tid; i2 < 64 * 9; i2 += 256) {
        int pix = i2 / 9, k = i2 % 9;
        int i = k / 3, j = k - i * 3;
        float ox = offs[pix][0];
        if (i >= 1) ox += offs[pix][1];
        if (i >= 2) ox += offs[pix][2];
        float oy = offs[pix][3];
        if (j >= 1) oy += offs[pix][4];
        if (j >= 2) oy += offs[pix][5];
        const float step = 2.0f / 63.0f;
        float bxn = -1.0f + pix * step;
        float byn = -1.0f + h * step;
        float gx = fmaf(bxn + ox, 32.0f, 31.5f);
        float gy = fmaf(byn + oy, 32.0f, 31.5f);
        float x0f = floorf(gx), y0f = floorf(gy);
        float wx = gx - x0f, wy = gy - y0f;
        int ix0 = (int)x0f, iy0 = (int)y0f;
        int ix1 = ix0 + 1, iy1 = iy0 + 1;
        float fx0 = ((unsigned)ix0 < 64u) ? 1.f : 0.f;
        float fx1 = ((unsigned)ix1 < 64u) ? 1.f : 0.f;
        float fy0 = ((unsigned)iy0 < 64u) ? 1.f : 0.f;
        float fy1 = ((unsigned)iy1 < 64u) ? 1.f : 0.f;
        float4v wv;
        wv[0] = (1.f - wy) * (1.f - wx) * fy0 * fx0;
        wv[1] = (1.f - wy) * wx * fy0 * fx1;
        wv[2] = wy * (1.f - wx) * fy1 * fx0;
        wv[3] = wy * wx * fy1 * fx1;
        int cx0 = min(max(ix0, 0), 63), cx1 = min(max(ix1, 0), 63);
        int cy0 = min(max(iy0, 0), 63), cy1 = min(max(iy1, 0), 63);
        twt[pix][k] = wv;
        tbs[pix][k] = make_int4((cy0 * 64 + cx0) * 64, (cy0 * 64 + cx1) * 64,
                                (cy1 * 64 + cx0) * 64, (cy1 * 64 + cx1) * 64);
    }
    __syncthreads();

    // -- main loop setup --
    int wave = tid >> 6, lane = tid & 63;
    int wo = wave & 1;                // o half (64 rows each)
    int wp = wave >> 1;               // pixel half (32 each)
    int mrow = lane & 15;
    int q8 = (lane >> 4) * 8;

    // A staging: thread -> rows (tid>>2), (tid>>2)+64; col group (tid&3)*8
    int ar = tid >> 2;
    int ag = (tid & 3) * 8;
    const u16* aptr0 = Wb + (size_t)ar * KD + ag;
    const u16* aptr1 = aptr0 + (size_t)64 * KD;
    int asto = ar * 32 + ag;

    // B staging: thread -> pixel (tid>>2), 32-ch quarter (tid&3)
    int pixB = tid >> 2;              // 0..63
    int t4 = tid & 3;
    int t4o = t4 * 4;                 // u32 offset within each 64B chunk-slot
    const u32* xb = (const u32*)(xt + (((size_t)b << 12) * (size_t)CH));  // bf16 pairs
    int bwb = pixB * LDBp + t4 * 8;   // write base (u16); + q*32 per chunk

    float4v acc[4][2];
    #pragma unroll
    for (int sm = 0; sm < 4; ++sm)
        #pragma unroll
        for (int sn = 0; sn < 2; ++sn)
            acc[sm][sn] = (float4v){0.f, 0.f, 0.f, 0.f};

    float4v wv;
    int4 bv;
    uint4 u[4][4];                    // [corner][chunk] - static indices only

    auto burst = [&](int t) {         // issue 16 gathers + read tap tables
        wv = twt[pixB][t];
        bv = tbs[pixB][t];
        #pragma unroll
        for (int q = 0; q < 4; ++q) {
            u[0][q] = *(const uint4*)(xb + bv.x + q * 16 + t4o);
            u[1][q] = *(const uint4*)(xb + bv.y + q * 16 + t4o);
            u[2][q] = *(const uint4*)(xb + bv.z + q * 16 + t4o);
            u[3][q] = *(const uint4*)(xb + bv.w + q * 16 + t4o);
        }
    };

    auto blendq = [&](const uint4& a0, const uint4& a1, const uint4& a2,
                      const uint4& a3, int col, u16* lBw) {
        const u32* p00 = (const u32*)&a0;
        const u32* p01 = (const u32*)&a1;
        const u32* p10 = (const u32*)&a2;
        const u32* p11 = (const u32*)&a3;
        u32 outp[4];
        #pragma unroll
        for (int j = 0; j < 4; ++j) {
            float2v p = unpk(p00[j]) * wv[0];
            p += unpk(p01[j]) * wv[1];
            p += unpk(p10[j]) * wv[2];
            p += unpk(p11[j]) * wv[3];
            outp[j] = pack_bf16(p.x, p.y);
        }
        *(uint4*)&lBw[bwb + col] = *(const uint4*)outp;
    };

    auto stepA = [&](int kk, uint4& c0, uint4& c1, uint4& n0, uint4& n1, u16* lAc) {
        *(uint4*)&lAc[asto] = c0;
        *(uint4*)&lAc[asto + 64 * 32] = c1;
        if (kk + 1 < 36) {
            n0 = *(const uint4*)(aptr0 + (size_t)(kk + 1) * 32);
            n1 = *(const uint4*)(aptr1 + (size_t)(kk + 1) * 32);
        }
    };

    auto mfma_step = [&](const u16* lAc, const u16* lBr, int col) {
        short8 af[4], bfv[2];
        #pragma unroll
        for (int i = 0; i < 4; ++i)
            af[i] = *(const short8*)&lAc[(wo * 64 + i * 16 + mrow) * 32 + q8];
        #pragma unroll
        for (int sn = 0; sn < 2; ++sn)
            bfv[sn] = *(const short8*)&lBr[(wp * 32 + sn * 16 + mrow) * LDBp + col + q8];
        #pragma unroll
        for (int i = 0; i < 4; ++i)
            #pragma unroll
            for (int sn = 0; sn < 2; ++sn)
                acc[i][sn] = __builtin_amdgcn_mfma_f32_16x16x32_bf16(af[i], bfv[sn],
                                                                    acc[i][sn], 0, 0, 0);
    };

    // prologue: tap 0 burst + blend into lB[0]; first A step into regs
    uint4 aC0 = *(const uint4*)aptr0;
    uint4 aC1 = *(const uint4*)aptr1;
    uint4 aN0, aN1;
    burst(0);
    {
        u16* lBw = &lB[0][0];
        blendq(u[0][0], u[1][0], u[2][0], u[3][0], 0,  lBw);
        blendq(u[0][1], u[1][1], u[2][1], u[3][1], 32, lBw);
        blendq(u[0][2], u[1][2], u[2][2], u[3][2], 64, lBw);
        blendq(u[0][3], u[1][3], u[2][3], u[3][3], 96, lBw);
    }

    for (int t = 0; t < 9; ++t) {
        int kk = t * 4;
        const u16* lBr = &lB[t & 1][0];
        u16* lBw = &lB[(t + 1) & 1][0];
        u16* lA0 = &lA[0][0];
        u16* lA1 = &lA[1][0];
        bool more = t < 8;

        // s = 0: burst next tap's gathers (max slack), stage A
        if (more) burst(t + 1);
        stepA(kk, aC0, aC1, aN0, aN1, lA0);
        BAR_LDS();
        mfma_step(lA0, lBr, 0);

        // s = 1
        stepA(kk + 1, aN0, aN1, aC0, aC1, lA1);
        BAR_LDS();
        mfma_step(lA1, lBr, 32);

        // s = 2: blend first half of next tap's B tile
        stepA(kk + 2, aC0, aC1, aN0, aN1, lA0);
        if (more) {
            blendq(u[0][0], u[1][0], u[2][0], u[3][0], 0,  lBw);
            blendq(u[0][1], u[1][1], u[2][1], u[3][1], 32, lBw);
        }
        BAR_LDS();
        mfma_step(lA0, lBr, 64);

        // s = 3: blend second half
        stepA(kk + 3, aN0, aN1, aC0, aC1, lA1);
        if (more) {
            blendq(u[0][2], u[1][2], u[2][2], u[3][2], 64, lBw);
            blendq(u[0][3], u[1][3], u[2][3], u[3][3], 96, lBw);
        }
        BAR_LDS();
        mfma_step(lA1, lBr, 96);
    }

    // epilogue: C/D layout col=lane&15 (pixel), row=(lane>>4)*4+r (o)
    #pragma unroll
    for (int sm = 0; sm < 4; ++sm) {
        int o = wo * 64 + sm * 16 + (lane >> 4) * 4;
        #pragma unroll
        for (int sn = 0; sn < 2; ++sn) {
            int pcol = m0 + wp * 32 + sn * 16 + mrow;
            int rem = pcol & 4095;
            float* op = out + (((size_t)b * OO) << 12) + rem;
            #pragma unroll
            for (int r = 0; r < 4; ++r)
                op[(size_t)(o + r) << 12] = acc[sm][sn][r] + b_main[o + r];
        }
    }
}

extern "C" void kernel_launch(void* const* d_in, const int* in_sizes, int n_in,
                              void* d_out, int out_size, void* d_ws, size_t ws_size,
                              hipStream_t stream) {
    const float* x      = (const float*)d_in[0];
    const float* w_off  = (const float*)d_in[1];
    const float* b_off  = (const float*)d_in[2];
    const float* w_main = (const float*)d_in[3];
    const float* b_main = (const float*)d_in[4];
    float* out = (float*)d_out;

    char* ws = (char*)d_ws;
    __hip_bfloat16* xt = (__hip_bfloat16*)ws;                         // 8 MB
    float* partial = (float*)(ws + 8388608);                          // 3 MB
    u16* Wb   = (u16*)(ws + 8388608 + 3145728);                       // 288 KB

    prep_kernel<<<1600, 256, 0, stream>>>(x, w_off, w_main, xt, partial, Wb);
    fused_gemm_kernel<<<MPIX / 64, 256, 0, stream>>>(xt, partial, b_off, Wb, b_main, out);
}

// Round 10
// 125.141 us; speedup vs baseline: 1.5397x; 1.0080x over previous
//
#include <hip/hip_runtime.h>
#include <hip/hip_bf16.h>
#include <stdint.h>

typedef unsigned short u16;
typedef unsigned int u32;
typedef __attribute__((ext_vector_type(8))) short short8;
typedef __attribute__((ext_vector_type(4))) float float4v;
typedef __attribute__((ext_vector_type(2))) float float2v;

#define CH 128
#define OO 128
#define KD 1152      // 9*128
#define MPIX 32768   // 8*64*64
#define LDBp 136     // lB row stride in u16 (128 ch + 8 pad: 2-way-free b128 reads)

// lA index with XOR swizzle: 64-col rows (128B stride) are 16-way bank
// conflicted raw; XOR of byte-bits 4-6 with row&7 spreads 8 rows across
// 8 distinct 16B slots -> 2-way (free). Same formula on write AND read.
#define LDA_SW(row, col) ((row) * 64 + ((col) ^ (((row) & 7) << 3)))

// Barrier without vmcnt drain (LDS-only fence). Global loads here are
// register-destined; compiler inserts counted vmcnt before each use.
#define BAR_LDS() do { \
    asm volatile("s_waitcnt lgkmcnt(0)" ::: "memory"); \
    __builtin_amdgcn_s_barrier(); \
} while (0)

__device__ __forceinline__ u16 f2bf(float v) {
    __hip_bfloat16 h = __float2bfloat16(v);
    return *reinterpret_cast<u16*>(&h);
}

__device__ __forceinline__ float bf_lo(u32 u) {      // low bf16 of pair -> f32 (exact)
    u32 t = u << 16;
    return __builtin_bit_cast(float, t);
}
__device__ __forceinline__ float bf_hi(u32 u) {      // high bf16 of pair -> f32 (exact)
    u32 t = u & 0xffff0000u;
    return __builtin_bit_cast(float, t);
}
__device__ __forceinline__ float2v unpk(u32 u) {
    float2v r;
    r.x = bf_lo(u);
    r.y = bf_hi(u);
    return r;
}
// pack two f32 -> bf16 pair; scalar casts fuse to v_cvt_pk_bf16_f32
__device__ __forceinline__ u32 pack_bf16(float lo, float hi) {
    return (u32)f2bf(lo) | ((u32)f2bf(hi) << 16);
}

// ---------------- merged prep: transpose + offset_conv + wreorder ----------------
__global__ __launch_bounds__(256) void prep_kernel(const float* __restrict__ x,
                                                   const float* __restrict__ w_off,
                                                   const float* __restrict__ w_main,
                                                   __hip_bfloat16* __restrict__ xt,
                                                   float* __restrict__ partial,
                                                   u16* __restrict__ Wb) {
    __shared__ float st[64][65];
    int tid = threadIdx.x;
    int bid = blockIdx.x;

    if (bid < 512) {
        // ---- transpose ----
        int bh = bid;                     // b*64 + h
        int b = bh >> 6;
        int h = bh & 63;
        const float* xb = x + ((size_t)b * CH) * 4096 + (size_t)h * 64;
        u32* xo32 = (u32*)(xt + ((size_t)bh << 6) * CH);   // row stride 64 u32
        for (int cc0 = 0; cc0 < 128; cc0 += 64) {
            #pragma unroll
            for (int step = 0; step < 16; ++step) {
                int cl = (tid >> 6) + step * 4;
                int w = tid & 63;
                st[cl][w] = xb[(size_t)(cc0 + cl) * 4096 + w];
            }
            __syncthreads();
            #pragma unroll
            for (int step = 0; step < 8; ++step) {
                int w = (tid >> 5) + step * 8;
                int p = tid & 31;
                u32 pair = pack_bf16(st[2 * p][w], st[2 * p + 1][w]);
                xo32[(size_t)w * 64 + (cc0 >> 1) + p] = pair;
            }
            __syncthreads();
        }
    } else if (bid < 1024) {
        // ---- offset conv ----
        int idx = bid - 512;
        int m = (idx & 127) * 256 + tid;
        int chunk = idx >> 7;             // 0..3, 32 channels each
        int b = m >> 12;
        int hw = m & 4095;
        int h = hw >> 6;
        int w = hw & 63;
        float acc[6] = {0.f, 0.f, 0.f, 0.f, 0.f, 0.f};
        int c0 = chunk * 32;
        for (int c = c0; c < c0 + 32; ++c) {
            const float* xc = x + ((size_t)(b * CH + c) << 12);
            float xv[9];
            #pragma unroll
            for (int dy = 0; dy < 3; ++dy) {
                int yy = h + dy - 1;
                bool vy = (unsigned)yy < 64u;
                #pragma unroll
                for (int dx = 0; dx < 3; ++dx) {
                    int xx = w + dx - 1;
                    bool vv = vy && ((unsigned)xx < 64u);
                    xv[dy * 3 + dx] = vv ? xc[yy * 64 + xx] : 0.f;
                }
            }
            const float* wb = w_off + (size_t)c * 9;
            #pragma unroll
            for (int s = 0; s < 6; ++s) {
                int chn = (s < 3) ? s * 6 : (s - 3) * 2 + 1;
                const float* wp = wb + (size_t)chn * (CH * 9);
                float a = acc[s];
                #pragma unroll
                for (int t = 0; t < 9; ++t) a = fmaf(xv[t], wp[t], a);
                acc[s] = a;
            }
        }
        float* po = partial + ((size_t)(chunk << 15) + m) * 6;
        #pragma unroll
        for (int s = 0; s < 6; ++s) po[s] = acc[s];
    } else {
        // ---- weight reorder ----
        int idx = (bid - 1024) * 256 + tid;
        if (idx < OO * KD) {
            int o = idx / KD;
            int r = idx - o * KD;
            int k = r >> 7;
            int c = r & 127;
            Wb[idx] = f2bf(w_main[(size_t)o * KD + c * 9 + k]);
        }
    }
}

// ---------------- fused deformable-sample + GEMM (K-step 64, 18 barriers) ----------------
// One block = 64 pixels x all 128 outputs; 512 blocks = 2/CU.
// XCD-affinity: bid&7 = image -> per-XCD L2-resident xt slice.
// Per tap (K=128): TWO 64-col steps, each {stage A-tile half, barrier, 16 MFMA}.
// B staged per tap: 16-uint4 gather burst at step 0, blended at step 1.
// lA XOR-swizzled (write+read); tbs packed to u32/tap to fit 2 blocks/CU LDS.
__global__ __launch_bounds__(256, 2) void fused_gemm_kernel(const __hip_bfloat16* __restrict__ xt,
                                                            const float* __restrict__ partial,
                                                            const float* __restrict__ b_off,
                                                            const u16* __restrict__ Wb,
                                                            const float* __restrict__ b_main,
                                                            float* __restrict__ out) {
    __shared__ float offs[64][6];
    __shared__ __align__(16) float4v twt[64][9];   // bilinear weights per (pix, tap)
    __shared__ u32 tbs[64][9];                     // packed corner coords (cx0,cy0,cx1,cy1)
    __shared__ __align__(16) u16 lA[2][128 * 64];  // weight tile dbuf (64 cols, swizzled)
    __shared__ __align__(16) u16 lB[2][64 * LDBp]; // sample tile dbuf (per tap)

    int tid = threadIdx.x;
    int orig = blockIdx.x;
    int b = orig & 7;                 // image == XCD
    int h = orig >> 3;                // row within image (0..63)
    int m0 = ((b << 6) + h) << 6;     // first pixel index

    // -- prologue 1: gather offsets (6 per pixel) --
    for (int idx = tid; idx < 64 * 6; idx += 256) {
        int pix = idx / 6, s = idx % 6;
        int m = m0 + pix;
        int chn = (s < 3) ? s * 6 : (s - 3) * 2 + 1;
        float v = b_off[chn];
        #pragma unroll
        for (int q = 0; q < 4; ++q) v += partial[((size_t)(q << 15) + m) * 6 + s];
        offs[pix][s] = v;
    }
    __syncthreads();

    // -- prologue 2: per-(pix,tap) bilinear weights + packed corner coords --
    for (int i2 = tid; i2 < 64 * 9; i2 += 256) {
        int pix = i2 / 9, k = i2 % 9;
        int i = k / 3, j = k - i * 3;
        float ox = offs[pix][0];
        if (i >= 1) ox += offs[pix][1];
        if (i >= 2) ox += offs[pix][2];
        float oy = offs[pix][3];
        if (j >= 1) oy += offs[pix][4];
        if (j >= 2) oy += offs[pix][5];
        const float step = 2.0f / 63.0f;
        float bxn = -1.0f + pix * step;
        float byn = -1.0f + h * step;
        float gx = fmaf(bxn + ox, 32.0f, 31.5f);
        float gy = fmaf(byn + oy, 32.0f, 31.5f);
        float x0f = floorf(gx), y0f = floorf(gy);
        float wx = gx - x0f, wy = gy - y0f;
        int ix0 = (int)x0f, iy0 = (int)y0f;
        int ix1 = ix0 + 1, iy1 = iy0 + 1;
        float fx0 = ((unsigned)ix0 < 64u) ? 1.f : 0.f;
        float fx1 = ((unsigned)ix1 < 64u) ? 1.f : 0.f;
        float fy0 = ((unsigned)iy0 < 64u) ? 1.f : 0.f;
        float fy1 = ((unsigned)iy1 < 64u) ? 1.f : 0.f;
        float4v wv;
        wv[0] = (1.f - wy) * (1.f - wx) * fy0 * fx0;
        wv[1] = (1.f - wy) * wx * fy0 * fx1;
        wv[2] = wy * (1.f - wx) * fy1 * fx0;
        wv[3] = wy * wx * fy1 * fx1;
        int cx0 = min(max(ix0, 0), 63), cx1 = min(max(ix1, 0), 63);
        int cy0 = min(max(iy0, 0), 63), cy1 = min(max(iy1, 0), 63);
        twt[pix][k] = wv;
        tbs[pix][k] = (u32)cx0 | ((u32)cy0 << 8) | ((u32)cx1 << 16) | ((u32)cy1 << 24);
    }
    __syncthreads();

    // -- main loop setup --
    int wave = tid >> 6, lane = tid & 63;
    int wo = wave & 1;                // o half (64 rows each)
    int wp = wave >> 1;               // pixel half (32 each)
    int mrow = lane & 15;
    int q8 = (lane >> 4) * 8;

    // A staging: thread -> rows (tid>>2), (tid>>2)+64; col groups (tid&3)*8, +32
    int ar = tid >> 2;
    int ag = (tid & 3) * 8;
    const u16* aptr0 = Wb + (size_t)ar * KD + ag;
    const u16* aptr1 = aptr0 + (size_t)64 * KD;

    // B staging: thread -> pixel (tid>>2), 32-ch quarter (tid&3)
    int pixB = tid >> 2;              // 0..63
    int t4 = tid & 3;
    int t4o = t4 * 4;                 // u32 offset within each 64B chunk-slot
    const u32* xb = (const u32*)(xt + (((size_t)b << 12) * (size_t)CH));  // bf16 pairs
    int bwb = pixB * LDBp + t4 * 8;   // write base (u16); + q*32 per chunk

    float4v acc[4][2];
    #pragma unroll
    for (int sm = 0; sm < 4; ++sm)
        #pragma unroll
        for (int sn = 0; sn < 2; ++sn)
            acc[sm][sn] = (float4v){0.f, 0.f, 0.f, 0.f};

    float4v wv;
    uint4 u[4][4];                    // [corner][chunk] - static indices only

    auto burst = [&](int t) {         // issue 16 gathers + read tap tables
        wv = twt[pixB][t];
        u32 pc = tbs[pixB][t];
        int cx0 = pc & 255, cy0 = (pc >> 8) & 255;
        int cx1 = (pc >> 16) & 255, cy1 = (pc >> 24) & 255;
        int b00 = ((cy0 << 6) + cx0) << 6;
        int b01 = ((cy0 << 6) + cx1) << 6;
        int b10 = ((cy1 << 6) + cx0) << 6;
        int b11 = ((cy1 << 6) + cx1) << 6;
        #pragma unroll
        for (int q = 0; q < 4; ++q) {
            u[0][q] = *(const uint4*)(xb + b00 + q * 16 + t4o);
            u[1][q] = *(const uint4*)(xb + b01 + q * 16 + t4o);
            u[2][q] = *(const uint4*)(xb + b10 + q * 16 + t4o);
            u[3][q] = *(const uint4*)(xb + b11 + q * 16 + t4o);
        }
    };

    auto blendq = [&](const uint4& a0, const uint4& a1, const uint4& a2,
                      const uint4& a3, int col, u16* lBw) {
        const u32* p00 = (const u32*)&a0;
        const u32* p01 = (const u32*)&a1;
        const u32* p10 = (const u32*)&a2;
        const u32* p11 = (const u32*)&a3;
        u32 outp[4];
        #pragma unroll
        for (int j = 0; j < 4; ++j) {
            float2v p = unpk(p00[j]) * wv[0];
            p += unpk(p01[j]) * wv[1];
            p += unpk(p10[j]) * wv[2];
            p += unpk(p11[j]) * wv[3];
            outp[j] = pack_bf16(p.x, p.y);
        }
        *(uint4*)&lBw[bwb + col] = *(const uint4*)outp;
    };

    // stage 64-col A half-tile (4 writes, swizzled) + prefetch next (4 loads)
    auto stageA = [&](int kk, uint4& c0, uint4& c1, uint4& c2, uint4& c3,
                      uint4& n0, uint4& n1, uint4& n2, uint4& n3, u16* lAc) {
        *(uint4*)&lAc[LDA_SW(ar, ag)]           = c0;
        *(uint4*)&lAc[LDA_SW(ar, ag + 32)]      = c1;
        *(uint4*)&lAc[LDA_SW(ar + 64, ag)]      = c2;
        *(uint4*)&lAc[LDA_SW(ar + 64, ag + 32)] = c3;
        if (kk + 1 < 18) {
            const u16* p0 = aptr0 + (size_t)(kk + 1) * 64;
            const u16* p1 = aptr1 + (size_t)(kk + 1) * 64;
            n0 = *(const uint4*)(p0);
            n1 = *(const uint4*)(p0 + 32);
            n2 = *(const uint4*)(p1);
            n3 = *(const uint4*)(p1 + 32);
        }
    };

    // 16 MFMAs over a 64-col step: p = K-half within step
    auto mfma_step = [&](const u16* lAc, const u16* lBr, int colB) {
        #pragma unroll
        for (int p = 0; p < 2; ++p) {
            short8 af[4], bfv[2];
            #pragma unroll
            for (int i = 0; i < 4; ++i) {
                int row = wo * 64 + i * 16 + mrow;
                af[i] = *(const short8*)&lAc[LDA_SW(row, p * 32 + q8)];
            }
            #pragma unroll
            for (int sn = 0; sn < 2; ++sn)
                bfv[sn] = *(const short8*)&lBr[(wp * 32 + sn * 16 + mrow) * LDBp +
                                               colB + p * 32 + q8];
            #pragma unroll
            for (int i = 0; i < 4; ++i)
                #pragma unroll
                for (int sn = 0; sn < 2; ++sn)
                    acc[i][sn] = __builtin_amdgcn_mfma_f32_16x16x32_bf16(af[i], bfv[sn],
                                                                        acc[i][sn], 0, 0, 0);
        }
    };

    // prologue: tap 0 burst + blend into lB[0]; first A step into regs
    uint4 aC0 = *(const uint4*)(aptr0);
    uint4 aC1 = *(const uint4*)(aptr0 + 32);
    uint4 aC2 = *(const uint4*)(aptr1);
    uint4 aC3 = *(const uint4*)(aptr1 + 32);
    uint4 aN0, aN1, aN2, aN3;
    burst(0);
    {
        u16* lBw = &lB[0][0];
        blendq(u[0][0], u[1][0], u[2][0], u[3][0], 0,  lBw);
        blendq(u[0][1], u[1][1], u[2][1], u[3][1], 32, lBw);
        blendq(u[0][2], u[1][2], u[2][2], u[3][2], 64, lBw);
        blendq(u[0][3], u[1][3], u[2][3], u[3][3], 96, lBw);
    }

    for (int t = 0; t < 9; ++t) {
        int kk = t * 2;
        const u16* lBr = &lB[t & 1][0];
        u16* lBw = &lB[(t + 1) & 1][0];
        u16* lA0 = &lA[0][0];
        u16* lA1 = &lA[1][0];
        bool more = t < 8;

        // step 0: cols [0,64) of this tap; burst next tap's gathers first
        if (more) burst(t + 1);
        stageA(kk, aC0, aC1, aC2, aC3, aN0, aN1, aN2, aN3, lA0);
        BAR_LDS();
        mfma_step(lA0, lBr, 0);

        // step 1: cols [64,128); blend next tap's B tile
        stageA(kk + 1, aN0, aN1, aN2, aN3, aC0, aC1, aC2, aC3, lA1);
        if (more) {
            blendq(u[0][0], u[1][0], u[2][0], u[3][0], 0,  lBw);
            blendq(u[0][1], u[1][1], u[2][1], u[3][1], 32, lBw);
            blendq(u[0][2], u[1][2], u[2][2], u[3][2], 64, lBw);
            blendq(u[0][3], u[1][3], u[2][3], u[3][3], 96, lBw);
        }
        BAR_LDS();
        mfma_step(lA1, lBr, 64);
    }

    // epilogue: C/D layout col=lane&15 (pixel), row=(lane>>4)*4+r (o)
    #pragma unroll
    for (int sm = 0; sm < 4; ++sm) {
        int o = wo * 64 + sm * 16 + (lane >> 4) * 4;
        #pragma unroll
        for (int sn = 0; sn < 2; ++sn) {
            int pcol = m0 + wp * 32 + sn * 16 + mrow;
            int rem = pcol & 4095;
            float* op = out + (((size_t)b * OO) << 12) + rem;
            #pragma unroll
            for (int r = 0; r < 4; ++r)
                op[(size_t)(o + r) << 12] = acc[sm][sn][r] + b_main[o + r];
        }
    }
}

extern "C" void kernel_launch(void* const* d_in, const int* in_sizes, int n_in,
                              void* d_out, int out_size, void* d_ws, size_t ws_size,
                              hipStream_t stream) {
    const float* x      = (const float*)d_in[0];
    const float* w_off  = (const float*)d_in[1];
    const float* b_off  = (const float*)d_in[2];
    const float* w_main = (const float*)d_in[3];
    const float* b_main = (const float*)d_in[4];
    float* out = (float*)d_out;

    char* ws = (char*)d_ws;
    __hip_bfloat16* xt = (__hip_bfloat16*)ws;                         // 8 MB
    float* partial = (float*)(ws + 8388608);                          // 3 MB
    u16* Wb   = (u16*)(ws + 8388608 + 3145728);                       // 288 KB

    prep_kernel<<<1600, 256, 0, stream>>>(x, w_off, w_main, xt, partial, Wb);
    fused_gemm_kernel<<<MPIX / 64, 256, 0, stream>>>(xt, partial, b_off, Wb, b_main, out);
}